// Round 1
// baseline (2174.221 us; speedup 1.0000x reference)
//
#include <hip/hip_runtime.h>
#include <hip/hip_bf16.h>
#include <stdint.h>

typedef __attribute__((ext_vector_type(8))) short bf16x8;
typedef __attribute__((ext_vector_type(4))) float f32x4;
typedef unsigned short u16;

__device__ __forceinline__ u16 f2bf(float x) {
  unsigned u = __float_as_uint(x);
  unsigned r = (u + 0x7FFFu + ((u >> 16) & 1u)) >> 16;
  return (u16)r;
}

__device__ __forceinline__ void gl_lds16(const void* g, void* l) {
  __builtin_amdgcn_global_load_lds((const __attribute__((address_space(1))) void*)g,
                                   (__attribute__((address_space(3))) void*)l, 16, 0, 0);
}

// ---------------- small setup kernels ----------------

__global__ void zero_f32_kernel(float* p, int n) {
  int i = blockIdx.x * blockDim.x + threadIdx.x;
  if (i < n) p[i] = 0.f;
}

__global__ void init_nbr_kernel(int* nbr, int total, int N) {
  for (int i = blockIdx.x * blockDim.x + threadIdx.x; i < total; i += gridDim.x * blockDim.x)
    nbr[i] = N;
}

__global__ void scatter_nbr_kernel(const int* __restrict__ in_idx, const int* __restrict__ out_idx,
                                   int* __restrict__ nbr, int N, int P, int NPAD) {
  const int total = 27 * P;
  for (int i = blockIdx.x * blockDim.x + threadIdx.x; i < total; i += gridDim.x * blockDim.x) {
    const int o = out_idx[i];
    if ((unsigned)o < (unsigned)N) {
      const int k = i / P;
      nbr[(size_t)k * NPAD + o] = in_idx[i];
    }
  }
}

__global__ void cvt_feats_kernel(const float* __restrict__ F, u16* __restrict__ X0, int N) {
  const int total = (N + 1) * 64;  // float4 groups of [N+1][256]
  for (int i = blockIdx.x * blockDim.x + threadIdx.x; i < total; i += gridDim.x * blockDim.x) {
    const int r = i >> 6;
    ushort4 o;
    if (r < N) {
      const float4 v = ((const float4*)F)[i];
      o.x = f2bf(v.x); o.y = f2bf(v.y); o.z = f2bf(v.z); o.w = f2bf(v.w);
    } else {
      o.x = 0; o.y = 0; o.z = 0; o.w = 0;
    }
    ((ushort4*)X0)[i] = o;
  }
}

// W: [27][CIN][512] f32  ->  Wt: [27][512][CIN] bf16 (transposed per offset)
__global__ void cvt_w_kernel(const float* __restrict__ W, u16* __restrict__ Wt, int CIN) {
  __shared__ float t[32][33];
  const int k = blockIdx.z;
  const int c0 = blockIdx.y * 32;  // CIN block
  const int n0 = blockIdx.x * 32;  // 512 block
  const int tx = threadIdx.x, ty = threadIdx.y;  // 32 x 8
  const float* Wk = W + (size_t)k * CIN * 512;
  for (int i = ty; i < 32; i += 8)
    t[i][tx] = Wk[(size_t)(c0 + i) * 512 + n0 + tx];
  __syncthreads();
  u16* Wtk = Wt + (size_t)k * 512 * CIN;
  for (int i = ty; i < 32; i += 8)
    Wtk[(size_t)(n0 + i) * CIN + c0 + tx] = f2bf(t[tx][i]);
}

// ---------------- conv GEMM: Y[o][n] = sum_k X[nbr[k][o]] @ Wt[k]^T ----------------
// m97-style 128x128 tile, BK=32, 4 waves (2x2 of 64x64), 16x16x32 bf16 MFMA,
// double-buffered LDS via global_load_lds(16B), chunk-XOR swizzle (2-way banks).

template <int CIN>
__global__ __launch_bounds__(256, 2) void conv_kernel(
    const u16* __restrict__ X,    // [(N+1)][CIN] bf16
    const u16* __restrict__ Wt,   // [27][512][CIN] bf16
    const int* __restrict__ nbr,  // [27][NPAD]
    float* __restrict__ Y,        // [N][512] f32
    int N, int NPAD) {
  constexpr int KK = CIN / 32;  // K-steps per offset
  constexpr int NSTEPS = 27 * KK;
  __shared__ __align__(16) u16 lds[16384];  // 2 bufs x (A 128x32 + B 128x32)

  const int tid = threadIdx.x;
  const int lane = tid & 63;
  const int wv = tid >> 6;
  const int wm = wv >> 1, wn = wv & 1;
  const int bm = blockIdx.x >> 2;
  const int bn = blockIdx.x & 3;
  const int row0 = bm * 128;
  const int col0 = bn * 128;

  // staging geometry: instr i covers rows i*64 + tid/4; chunk = tid&3 (16B units)
  const int sc = tid & 3;
  int srow[2], scs[2];
  size_t boffg[2];
#pragma unroll
  for (int i = 0; i < 2; ++i) {
    srow[i] = i * 64 + (tid >> 2);
    scs[i] = (sc ^ ((srow[i] >> 1) & 3)) * 8;  // swizzled source chunk (elements)
    boffg[i] = (size_t)(col0 + srow[i]) * CIN + scs[i];
  }

  // ds_read fragment offsets (elements), with the same XOR swizzle
  const int lr = lane & 15;
  const int q = lane >> 4;
  int aoff[4], boff[4];
#pragma unroll
  for (int f = 0; f < 4; ++f) {
    const int ra = wm * 64 + f * 16 + lr;
    aoff[f] = ra * 32 + ((q ^ ((ra >> 1) & 3)) * 8);
    const int rb = wn * 64 + f * 16 + lr;
    boff[f] = 4096 + rb * 32 + ((q ^ ((rb >> 1) & 3)) * 8);
  }

  f32x4 acc[4][4];
#pragma unroll
  for (int a = 0; a < 4; ++a)
#pragma unroll
    for (int b = 0; b < 4; ++b) acc[a][b] = (f32x4){0.f, 0.f, 0.f, 0.f};

  size_t arow[2];
#pragma unroll
  for (int i = 0; i < 2; ++i)
    arow[i] = (size_t)nbr[row0 + srow[i]] * CIN;  // k = 0

  // prologue: stage step 0 into buf 0
#pragma unroll
  for (int i = 0; i < 2; ++i) {
    gl_lds16(X + arow[i] + scs[i], &lds[i * 2048 + wv * 512]);
    gl_lds16(Wt + boffg[i], &lds[4096 + i * 2048 + wv * 512]);
  }

  int cur = 0;
  for (int s = 0; s < NSTEPS; ++s) {
    __syncthreads();  // drains vmcnt -> buf[cur] ready; protects buf being overwritten
    const int ns = s + 1;
    if (ns < NSTEPS) {
      const int k = ns / KK;
      const int kk = ns % KK;
      if (kk == 0) {
        const int* nb = nbr + (size_t)k * NPAD + row0;
#pragma unroll
        for (int i = 0; i < 2; ++i) arow[i] = (size_t)nb[srow[i]] * CIN;
      }
      const int nxt = cur ^ 1;
      const int ko = kk * 32;
      const size_t kb = (size_t)k * (512 * CIN);
#pragma unroll
      for (int i = 0; i < 2; ++i) {
        gl_lds16(X + arow[i] + ko + scs[i], &lds[nxt * 8192 + i * 2048 + wv * 512]);
        gl_lds16(Wt + kb + boffg[i] + ko, &lds[nxt * 8192 + 4096 + i * 2048 + wv * 512]);
      }
    }
    // compute on buf[cur]
    const u16* lb = &lds[cur * 8192];
    bf16x8 av[4], bv[4];
#pragma unroll
    for (int f = 0; f < 4; ++f) av[f] = *(const bf16x8*)&lb[aoff[f]];
#pragma unroll
    for (int f = 0; f < 4; ++f) bv[f] = *(const bf16x8*)&lb[boff[f]];
#pragma unroll
    for (int a = 0; a < 4; ++a)
#pragma unroll
      for (int b = 0; b < 4; ++b)
        acc[a][b] = __builtin_amdgcn_mfma_f32_16x16x32_bf16(av[a], bv[b], acc[a][b], 0, 0, 0);
    cur ^= 1;
  }

  // epilogue: C/D layout col=lane&15, row=(lane>>4)*4+reg (m89-verified)
#pragma unroll
  for (int a = 0; a < 4; ++a) {
    const int r0 = row0 + wm * 64 + a * 16 + q * 4;
#pragma unroll
    for (int b = 0; b < 4; ++b) {
      const int c = col0 + wn * 64 + b * 16 + lr;
#pragma unroll
      for (int j = 0; j < 4; ++j) {
        const int r = r0 + j;
        if (r < N) Y[(size_t)r * 512 + c] = acc[a][b][j];
      }
    }
  }
}

// ---------------- BN + ReLU + pool ----------------

__global__ void bn_stats_kernel(const float* __restrict__ Y, float* __restrict__ st, int N) {
  const int t = threadIdx.x;  // channels 2t, 2t+1
  float s0 = 0.f, s1 = 0.f, q0 = 0.f, q1 = 0.f;
  for (int r = blockIdx.x; r < N; r += gridDim.x) {
    const float2 v = *(const float2*)&Y[(size_t)r * 512 + t * 2];
    s0 += v.x; s1 += v.y; q0 += v.x * v.x; q1 += v.y * v.y;
  }
  atomicAdd(&st[2 * t], s0);
  atomicAdd(&st[2 * t + 1], s1);
  atomicAdd(&st[512 + 2 * t], q0);
  atomicAdd(&st[512 + 2 * t + 1], q1);
}

__global__ void bn_finalize_kernel(const float* __restrict__ st, const float* __restrict__ g,
                                   const float* __restrict__ b, float* __restrict__ sc,
                                   float* __restrict__ sh, int N) {
  const int c = threadIdx.x;
  if (c < 512) {
    const float inv = 1.f / (float)N;
    const float m = st[c] * inv;
    const float v = st[512 + c] * inv - m * m;
    const float rs = rsqrtf(v + 1e-5f);
    const float s = rs * g[c];
    sc[c] = s;
    sh[c] = b[c] - m * s;
  }
}

__global__ void bn_norm_kernel(const float* __restrict__ Y, const float* __restrict__ sc,
                               const float* __restrict__ sh, u16* __restrict__ Xn, int N) {
  const int total = (N + 1) * 128;  // float4 groups of [N+1][512]
  for (int i = blockIdx.x * blockDim.x + threadIdx.x; i < total; i += gridDim.x * blockDim.x) {
    const int r = i >> 7;
    const int c = (i & 127) * 4;
    ushort4 o;
    if (r < N) {
      const float4 y = *(const float4*)&Y[(size_t)r * 512 + c];
      const float v0 = fmaxf(fmaf(y.x, sc[c + 0], sh[c + 0]), 0.f);
      const float v1 = fmaxf(fmaf(y.y, sc[c + 1], sh[c + 1]), 0.f);
      const float v2 = fmaxf(fmaf(y.z, sc[c + 2], sh[c + 2]), 0.f);
      const float v3 = fmaxf(fmaf(y.w, sc[c + 3], sh[c + 3]), 0.f);
      o.x = f2bf(v0); o.y = f2bf(v1); o.z = f2bf(v2); o.w = f2bf(v3);
    } else {
      o.x = 0; o.y = 0; o.z = 0; o.w = 0;
    }
    *(ushort4*)&Xn[(size_t)r * 512 + c] = o;
  }
}

// fused BN+ReLU of layer3 + segment_max via int atomicMax (vals >= 0)
__global__ void bn_norm_pool_kernel(const float* __restrict__ Y, const float* __restrict__ sc,
                                    const float* __restrict__ sh, const int* __restrict__ pool,
                                    float* __restrict__ out, int N) {
  const int total = N * 128;
  for (int i = blockIdx.x * blockDim.x + threadIdx.x; i < total; i += gridDim.x * blockDim.x) {
    const int r = i >> 7;
    const int c = (i & 127) * 4;
    const float4 y = *(const float4*)&Y[(size_t)r * 512 + c];
    const int p = pool[r];
    int* ob = (int*)&out[(size_t)p * 512 + c];
    const float v0 = fmaxf(fmaf(y.x, sc[c + 0], sh[c + 0]), 0.f);
    const float v1 = fmaxf(fmaf(y.y, sc[c + 1], sh[c + 1]), 0.f);
    const float v2 = fmaxf(fmaf(y.z, sc[c + 2], sh[c + 2]), 0.f);
    const float v3 = fmaxf(fmaf(y.w, sc[c + 3], sh[c + 3]), 0.f);
    atomicMax(&ob[0], __float_as_int(v0));
    atomicMax(&ob[1], __float_as_int(v1));
    atomicMax(&ob[2], __float_as_int(v2));
    atomicMax(&ob[3], __float_as_int(v3));
  }
}

// ---------------- host ----------------

extern "C" void kernel_launch(void* const* d_in, const int* in_sizes, int n_in,
                              void* d_out, int out_size, void* d_ws, size_t ws_size,
                              hipStream_t stream) {
  const float* feats = (const float*)d_in[0];
  const float* W1 = (const float*)d_in[1];
  const float* g1 = (const float*)d_in[2];
  const float* b1 = (const float*)d_in[3];
  const float* W2 = (const float*)d_in[4];
  const float* g2 = (const float*)d_in[5];
  const float* b2 = (const float*)d_in[6];
  const float* W3 = (const float*)d_in[7];
  const float* g3 = (const float*)d_in[8];
  const float* b3 = (const float*)d_in[9];
  const int* in_idx = (const int*)d_in[10];
  const int* out_idx = (const int*)d_in[11];
  const int* pool_idx = (const int*)d_in[12];
  float* out = (float*)d_out;

  const int N = in_sizes[0] / 256;
  const int P = in_sizes[10] / 27;
  const int NPAD = ((N + 127) / 128) * 128;

  // workspace carve (bytes, 512-aligned)
  char* w = (char*)d_ws;
  size_t off = 0;
  auto carve = [&](size_t bytes) {
    void* p = w + off;
    off += (bytes + 511) & ~(size_t)511;
    return p;
  };
  int* nbr = (int*)carve((size_t)27 * NPAD * 4);
  u16* X0 = (u16*)carve((size_t)(N + 1) * 256 * 2);
  u16* X1 = (u16*)carve((size_t)(N + 1) * 512 * 2);  // reused as X2 after conv2
  float* Y = (float*)carve((size_t)N * 512 * 4);
  u16* W1t = (u16*)carve((size_t)27 * 512 * 256 * 2);
  u16* W2t = (u16*)carve((size_t)27 * 512 * 512 * 2);
  u16* W3t = (u16*)carve((size_t)27 * 512 * 512 * 2);
  float* st0 = (float*)carve(1024 * 4);
  float* st1 = (float*)carve(1024 * 4);
  float* st2 = (float*)carve(1024 * 4);
  float* sc = (float*)carve(512 * 4);
  float* sh = (float*)carve(512 * 4);
  (void)ws_size; (void)n_in;

  const int convGrid = (NPAD / 128) * 4;

  // setup
  zero_f32_kernel<<<12, 256, 0, stream>>>(st0, 3072);  // st0,st1,st2 contiguous-ish (padded) -> zero separately below
  zero_f32_kernel<<<4, 256, 0, stream>>>(st1, 1024);
  zero_f32_kernel<<<4, 256, 0, stream>>>(st2, 1024);
  init_nbr_kernel<<<2048, 256, 0, stream>>>(nbr, 27 * NPAD, N);
  scatter_nbr_kernel<<<2048, 256, 0, stream>>>(in_idx, out_idx, nbr, N, P, NPAD);
  cvt_feats_kernel<<<2048, 256, 0, stream>>>(feats, X0, N);
  cvt_w_kernel<<<dim3(16, 8, 27), dim3(32, 8), 0, stream>>>(W1, W1t, 256);
  cvt_w_kernel<<<dim3(16, 16, 27), dim3(32, 8), 0, stream>>>(W2, W2t, 512);
  cvt_w_kernel<<<dim3(16, 16, 27), dim3(32, 8), 0, stream>>>(W3, W3t, 512);

  // layer 1
  conv_kernel<256><<<convGrid, 256, 0, stream>>>(X0, W1t, nbr, Y, N, NPAD);
  bn_stats_kernel<<<512, 256, 0, stream>>>(Y, st0, N);
  bn_finalize_kernel<<<1, 512, 0, stream>>>(st0, g1, b1, sc, sh, N);
  bn_norm_kernel<<<4096, 256, 0, stream>>>(Y, sc, sh, X1, N);

  // layer 2
  conv_kernel<512><<<convGrid, 256, 0, stream>>>(X1, W2t, nbr, Y, N, NPAD);
  bn_stats_kernel<<<512, 256, 0, stream>>>(Y, st1, N);
  bn_finalize_kernel<<<1, 512, 0, stream>>>(st1, g2, b2, sc, sh, N);
  bn_norm_kernel<<<4096, 256, 0, stream>>>(Y, sc, sh, X1, N);  // X2 aliases X1 (conv2 done)

  // layer 3 + pool
  conv_kernel<512><<<convGrid, 256, 0, stream>>>(X1, W3t, nbr, Y, N, NPAD);
  bn_stats_kernel<<<512, 256, 0, stream>>>(Y, st2, N);
  bn_finalize_kernel<<<1, 512, 0, stream>>>(st2, g3, b3, sc, sh, N);
  bn_norm_pool_kernel<<<4096, 256, 0, stream>>>(Y, sc, sh, pool_idx, out, N);
}